// Round 7
// baseline (246.464 us; speedup 1.0000x reference)
//
#include <hip/hip_runtime.h>

// ReactDiffDynamics: dUdt = a*lap(U) + U - U^3 - k - V ; dVdt = b*lap(V) + U - V
// Periodic 5-point Laplacian (jnp.roll semantics), B=64, H=W=512, fp32.
//
// v7: counted-vmcnt ring pipeline (T3/T4 pattern). Evidence: six structures
// (flat, serial, swizzle/NT, shuffle, reg-block, LDS tile) all ~73-80us with
// HBM 32%, VALU 12%, LDS 0 -> stall-dominated: loads and their consumers share
// one phase (every prior version drains vmcnt to 0 before compute; v6's
// __syncthreads emits the full vmcnt(0) drain). v7 keeps 2 chunks of
// global_load_lds DMA in flight ACROSS raw s_barriers (vmcnt(4), never 0):
//   LDS ring: 2ch x 16 row-slots x 512 (64 KB, 2 blocks/CU). Block = full W x
//   32-row segment, 8 steps x 4 rows. Step s: wait vmcnt(4) [chunk s+1 landed],
//   barrier, compute+store chunk s from LDS, barrier, issue DMA for chunk s+3.
//   Slot math: chunk c -> slots (4c..4c+3)&15; compute(s) reads (4s-1..4s+4)&15;
//   in-flight chunk s+2 writes (4s+8..4s+11)&15 (disjoint); chunk s+3
//   (overwrites 4s-1's stripe) issued only after post-compute barrier.
// W-halo periodic inside the 512-wide LDS row -> zero W/E global traffic.

constexpr int B = 64;
constexpr int H = 512;
constexpr int W = 512;
constexpr int PLANE = H * W;
constexpr int SEG   = 32;              // rows per block segment
constexpr int STEPS = SEG / 4;         // 8 chunks of 4 rows
constexpr int NSEG  = H / SEG;         // 16 segments per image
constexpr int GRID  = B * NSEG;        // 1024 blocks

__device__ __forceinline__ void async16(const float* src, float* dst_lds) {
    __builtin_amdgcn_global_load_lds(
        (const __attribute__((address_space(1))) void*)src,
        (__attribute__((address_space(3))) void*)dst_lds, 16, 0, 0);
}

__global__ __launch_bounds__(256) void react_diff_kernel(
    const float* __restrict__ x,       // (B, 2, H, W)
    const float* __restrict__ params,  // (B, 3)
    float* __restrict__ out)           // (B, 2, H, W)
{
    __shared__ float lds[2][16][W];    // 64 KB ring: [ch][row slot][col]

    const float inv_dx2 = 240.25f;     // 1/dx^2, dx = 2/31

    const int t    = threadIdx.x;
    const int lane = t & 63;
    const int wq   = (t >> 6) << 2;    // wave index * 4
    const int c    = t & 127;          // float4 column [0,128)
    const int rr2  = t >> 7;           // 0/1: row parity within chunk
    const int b    = blockIdx.x >> 4;  // image (block-uniform)
    const int seg  = blockIdx.x & (NSEG - 1);
    const int h0   = seg * SEG;

    const float* xb = x + (size_t)b * 2 * PLANE;
    float* oU = out + (size_t)b * 2 * PLANE;
    float* oV = oU + PLANE;

    // Stage chunk cn (4 rows x 2 channels = 16 KB) via LDS-DMA.
    // Wave w issues insts j=0..3; q=w*4+j selects (ch, row-in-chunk, half-row).
    // LDS dest is wave-uniform base + lane*16 (linear half-row) per HW rule.
    auto STAGE = [&](int cn) {
        const int base = 4 * cn;
        #pragma unroll
        for (int j = 0; j < 4; ++j) {
            const int q    = wq + j;           // 0..15
            const int ch   = q >> 3;
            const int rr   = (q >> 1) & 3;
            const int half = q & 1;
            const int g    = (h0 + base + rr) & (H - 1);   // periodic row
            const int slot = (base + rr) & 15;
            const float* src = xb + (size_t)ch * PLANE + (size_t)g * W
                             + half * 256 + lane * 4;
            async16(src, &lds[ch][slot][half * 256]);
        }
    };

    // prologue: chunks -1..2 in flight (16 loads/wave outstanding)
    STAGE(-1); STAGE(0); STAGE(1); STAGE(2);

    // block-uniform -> scalar loads
    const float ca = params[b * 3 + 0] * inv_dx2;
    const float cb = params[b * 3 + 1] * inv_dx2;
    const float pk = params[b * 3 + 2];

    const int cW = (c - 1) & 127;      // periodic west/east f4 columns
    const int cE = (c + 1) & 127;

    for (int s = 0; s < STEPS; ++s) {
        // chunk s+1 complete (newest 4 loads = chunk s+2 stay in flight);
        // in-order vmcnt retirement also drains prior stores first.
        asm volatile("s_waitcnt vmcnt(4)" ::: "memory");
        __builtin_amdgcn_s_barrier();     // raw: no compiler vmcnt(0) drain

        #pragma unroll
        for (int rv = 0; rv < 2; ++rv) {
            const int lr = 4 * s + rr2 + 2 * rv;   // local row 0..SEG-1
            const int sn = (4 * s + rr2 + 2 * rv - 1) & 15;
            const int sc = (4 * s + rr2 + 2 * rv) & 15;
            const int ss = (4 * s + rr2 + 2 * rv + 1) & 15;
            const size_t ro = (size_t)(h0 + lr) * W;

            float4 Un = *(const float4*)&lds[0][sn][c  * 4];
            float4 Uc = *(const float4*)&lds[0][sc][c  * 4];
            float4 Us = *(const float4*)&lds[0][ss][c  * 4];
            float4 UL = *(const float4*)&lds[0][sc][cW * 4];
            float4 UR = *(const float4*)&lds[0][sc][cE * 4];

            float4 Vn = *(const float4*)&lds[1][sn][c  * 4];
            float4 Vc = *(const float4*)&lds[1][sc][c  * 4];
            float4 Vs = *(const float4*)&lds[1][ss][c  * 4];
            float4 VL = *(const float4*)&lds[1][sc][cW * 4];
            float4 VR = *(const float4*)&lds[1][sc][cE * 4];

            float4 lap, d;

            lap.x = Un.x + Us.x + UL.w + Uc.y - 4.0f * Uc.x;
            lap.y = Un.y + Us.y + Uc.x + Uc.z - 4.0f * Uc.y;
            lap.z = Un.z + Us.z + Uc.y + Uc.w - 4.0f * Uc.z;
            lap.w = Un.w + Us.w + Uc.z + UR.x - 4.0f * Uc.w;
            d.x = ca * lap.x + Uc.x - Uc.x * Uc.x * Uc.x - pk - Vc.x;
            d.y = ca * lap.y + Uc.y - Uc.y * Uc.y * Uc.y - pk - Vc.y;
            d.z = ca * lap.z + Uc.z - Uc.z * Uc.z * Uc.z - pk - Vc.z;
            d.w = ca * lap.w + Uc.w - Uc.w * Uc.w * Uc.w - pk - Vc.w;
            ((float4*)(oU + ro))[c] = d;

            lap.x = Vn.x + Vs.x + VL.w + Vc.y - 4.0f * Vc.x;
            lap.y = Vn.y + Vs.y + Vc.x + Vc.z - 4.0f * Vc.y;
            lap.z = Vn.z + Vs.z + Vc.y + Vc.w - 4.0f * Vc.z;
            lap.w = Vn.w + Vs.w + Vc.z + VR.x - 4.0f * Vc.w;
            d.x = cb * lap.x + Uc.x - Vc.x;
            d.y = cb * lap.y + Uc.y - Vc.y;
            d.z = cb * lap.z + Uc.z - Vc.z;
            d.w = cb * lap.w + Uc.w - Vc.w;
            ((float4*)(oV + ro))[c] = d;
        }

        __builtin_amdgcn_s_barrier();     // all waves done reading chunk s-1 rows
        if (s <= STEPS - 3) STAGE(s + 3); // chunks 3..STEPS (last = south halo)
    }
}

extern "C" void kernel_launch(void* const* d_in, const int* in_sizes, int n_in,
                              void* d_out, int out_size, void* d_ws, size_t ws_size,
                              hipStream_t stream) {
    // d_in[0] = t (1 float, unused), d_in[1] = x (B,2,H,W), d_in[2] = params (B,3)
    const float* x      = (const float*)d_in[1];
    const float* params = (const float*)d_in[2];
    float* out          = (float*)d_out;

    react_diff_kernel<<<GRID, 256, 0, stream>>>(x, params, out);
}

// Round 8
// 232.662 us; speedup vs baseline: 1.0593x; 1.0593x over previous
//
#include <hip/hip_runtime.h>

// ReactDiffDynamics: dUdt = a*lap(U) + U - U^3 - k - V ; dVdt = b*lap(V) + U - V
// Periodic 5-point Laplacian (jnp.roll semantics), B=64, H=W=512, fp32.
//
// v8 = v1 + shuffle-halo, minus everything else. Evidence from 7 structures
// (flat / serial walk / swizzle+NT / shuffle / 2-row reg-block / LDS tile /
// counted-vmcnt DMA pipeline): all land 73-84us; effective app BW
// (262 MB read+write) ~3.5 TB/s invariant to request count (3x range),
// occupancy (18-77%), MLP, and pipelining; write-only fill = 6.7 TB/s same
// box. Diagnosis: mixed 50R/50W stream limit at the TCC/HBM boundary; time
// tracks app bytes only. Flat v1 is the band floor (zero staging overhead,
// max block turnover). v8 isolates the two measured intra-family deltas:
//   - shuffle W/E halo (v4: +, removes 4 of 12 vmem streams/thread)
//   - NO XCD swizzle (v3/v4: -, L3 absorbs cross-XCD halo reuse anyway)
// Plain float4 stores (NT measured as regression in v3).

constexpr int B = 64;
constexpr int H = 512;
constexpr int W = 512;
constexpr int W4 = W / 4;            // 128 float4 groups per row
constexpr int PLANE = H * W;
constexpr int GRID = B * H * W4 / 256;   // 16384 blocks

__global__ __launch_bounds__(256) void react_diff_kernel(
    const float* __restrict__ x,       // (B, 2, H, W)
    const float* __restrict__ params,  // (B, 3)
    float* __restrict__ out)           // (B, 2, H, W)
{
    const float inv_dx2 = 240.25f;     // 1/dx^2, dx = 2/31

    const int tid  = blockIdx.x * 256 + (int)threadIdx.x;  // [0, B*H*W4)
    const int lane = threadIdx.x & 63;
    const int wv   = tid & (W4 - 1);
    const int rem  = tid >> 7;          // tid / W4
    const int h    = rem & (H - 1);
    const int b    = rem >> 9;          // rem / H  (block-uniform)

    const int hn = (h == 0)     ? H - 1 : h - 1;   // roll(+1): f[h-1]
    const int hs = (h == H - 1) ? 0     : h + 1;   // roll(-1): f[h+1]
    const int w0 = wv * 4;
    const int wW = (wv == 0)      ? W - 1 : w0 - 1;  // west wrap column
    const int wE = (wv == W4 - 1) ? 0     : w0 + 4;  // east wrap column

    const float* Ub = x + (size_t)b * 2 * PLANE;
    const float* Vb = Ub + PLANE;

    const size_t rc = (size_t)h  * W;
    const size_t rn = (size_t)hn * W;
    const size_t rs = (size_t)hs * W;

    float4 Uc = ((const float4*)(Ub + rc))[wv];
    float4 Un = ((const float4*)(Ub + rn))[wv];
    float4 Us = ((const float4*)(Ub + rs))[wv];
    float4 Vc = ((const float4*)(Vb + rc))[wv];
    float4 Vn = ((const float4*)(Vb + rn))[wv];
    float4 Vs = ((const float4*)(Vb + rs))[wv];

    // W/E halo from neighbor lanes' registers; lane 0/63 fix up from memory
    // (their neighbor column lives in the adjacent wave / wrapped row edge).
    float Uw = __shfl_up(Uc.w, 1);
    float Vw = __shfl_up(Vc.w, 1);
    float Ue = __shfl_down(Uc.x, 1);
    float Ve = __shfl_down(Vc.x, 1);
    if (lane == 0 || lane == 63) {
        const int off = (lane == 0) ? wW : wE;   // correct global column for
        const float ub = Ub[rc + off];           // this lane's missing side
        const float vb = Vb[rc + off];
        if (lane == 0) { Uw = ub; Vw = vb; }
        else           { Ue = ub; Ve = vb; }
    }

    // block-uniform -> scalar loads
    const float ca = params[b * 3 + 0] * inv_dx2;
    const float cb = params[b * 3 + 1] * inv_dx2;
    const float pk = params[b * 3 + 2];

    float4 lapU, lapV;
    lapU.x = Un.x + Us.x + Uw   + Uc.y - 4.0f * Uc.x;
    lapU.y = Un.y + Us.y + Uc.x + Uc.z - 4.0f * Uc.y;
    lapU.z = Un.z + Us.z + Uc.y + Uc.w - 4.0f * Uc.z;
    lapU.w = Un.w + Us.w + Uc.z + Ue   - 4.0f * Uc.w;

    lapV.x = Vn.x + Vs.x + Vw   + Vc.y - 4.0f * Vc.x;
    lapV.y = Vn.y + Vs.y + Vc.x + Vc.z - 4.0f * Vc.y;
    lapV.z = Vn.z + Vs.z + Vc.y + Vc.w - 4.0f * Vc.z;
    lapV.w = Vn.w + Vs.w + Vc.z + Ve   - 4.0f * Vc.w;

    float4 dU, dV;
    dU.x = ca * lapU.x + Uc.x - Uc.x * Uc.x * Uc.x - pk - Vc.x;
    dU.y = ca * lapU.y + Uc.y - Uc.y * Uc.y * Uc.y - pk - Vc.y;
    dU.z = ca * lapU.z + Uc.z - Uc.z * Uc.z * Uc.z - pk - Vc.z;
    dU.w = ca * lapU.w + Uc.w - Uc.w * Uc.w * Uc.w - pk - Vc.w;

    dV.x = cb * lapV.x + Uc.x - Vc.x;
    dV.y = cb * lapV.y + Uc.y - Vc.y;
    dV.z = cb * lapV.z + Uc.z - Vc.z;
    dV.w = cb * lapV.w + Uc.w - Vc.w;

    float* ob = out + (size_t)b * 2 * PLANE;
    ((float4*)(ob + rc))[wv]         = dU;
    ((float4*)(ob + PLANE + rc))[wv] = dV;
}

extern "C" void kernel_launch(void* const* d_in, const int* in_sizes, int n_in,
                              void* d_out, int out_size, void* d_ws, size_t ws_size,
                              hipStream_t stream) {
    // d_in[0] = t (1 float, unused), d_in[1] = x (B,2,H,W), d_in[2] = params (B,3)
    const float* x      = (const float*)d_in[1];
    const float* params = (const float*)d_in[2];
    float* out          = (float*)d_out;

    react_diff_kernel<<<GRID, 256, 0, stream>>>(x, params, out);
}